// Round 4
// baseline (3430.126 us; speedup 1.0000x reference)
//
#include <hip/hip_runtime.h>
#include <math.h>

#define B 128
#define S 2048
#define V 800
#define E 128
#define H 64
#define NL 3
#define M (B*S)

typedef unsigned short ushort_t;

__device__ __forceinline__ float bf2f(unsigned short u){
  return __uint_as_float(((unsigned int)u) << 16);
}
__device__ __forceinline__ unsigned short f2bf(float f){
  unsigned int u = __float_as_uint(f);
  u += 0x7fff + ((u >> 16) & 1);          // round-to-nearest-even
  return (unsigned short)(u >> 16);
}
__device__ __forceinline__ float bcast_lane(float v, int j){
  return __int_as_float(__builtin_amdgcn_readlane(__float_as_int(v), j));
}
__device__ __forceinline__ float fast_tanh(float x){
  float e = __expf(2.f*x);
  return 1.f - 2.f*__builtin_amdgcn_rcpf(e+1.f);
}

// pre_emb[v][n] = emb[v]·w_ih[0,n,:] + b_ih[0,n] + b_hh[0,n],  n = d*64+i
__global__ __launch_bounds__(128) void k_pre_emb(const float* __restrict__ emb,
    const float* __restrict__ w_ih, const float* __restrict__ b_ih, const float* __restrict__ b_hh,
    float* __restrict__ pe)
{
  const int v = blockIdx.x;
  const int n = threadIdx.x;           // 0..127
  const float* er = emb + (size_t)v*E;
  const float* wr = w_ih + (size_t)n*E;   // layer 0 rows
  float acc = b_ih[n] + b_hh[n];
  #pragma unroll
  for (int e=0;e<E;e+=4){
    float4 ev = *(const float4*)(er+e);
    float4 wv = *(const float4*)(wr+e);
    acc = fmaf(ev.x, wv.x, acc);
    acc = fmaf(ev.y, wv.y, acc);
    acc = fmaf(ev.z, wv.z, acc);
    acc = fmaf(ev.w, wv.w, acc);
  }
  pe[(size_t)v*128 + n] = acc;
}

// partial mean/max pools over S-chunks
__global__ __launch_bounds__(128) void k_pool(const int* __restrict__ x, const float* __restrict__ emb,
      float* __restrict__ psum, float* __restrict__ pmax)
{
  const int b = blockIdx.x, c = blockIdx.y, e = threadIdx.x;
  const int* xb = x + (size_t)b*S + c*(S/16);
  float s=0.f, m=-INFINITY;
  for (int k=0;k<S/16;++k){
    int v = xb[k];
    float val = emb[(size_t)v*E + e];
    s += val; m = fmaxf(m,val);
  }
  psum[((size_t)b*16 + c)*E + e] = s;
  pmax[((size_t)b*16 + c)*E + e] = m;
}

// layer-0 input projection = gather from pre_emb table. pre[d][m][i]
__global__ __launch_bounds__(256) void k_gather0(const int* __restrict__ x, const float* __restrict__ pe,
      float* __restrict__ pre)
{
  const int m = blockIdx.x*4 + (threadIdx.x>>6);
  const int i = threadIdx.x & 63;
  const int v = x[m];
  const float* row = pe + (size_t)v*128;
  pre[(size_t)m*H + i]              = row[i];
  pre[((size_t)M + m)*H + i]        = row[64+i];
}

// recurrence: one wave per (d,b) chain. lane i owns output h[i]. y stored bf16.
__global__ __launch_bounds__(64) void k_rec(const float* __restrict__ pre,
                                            ushort_t* __restrict__ y,
                                            const float* __restrict__ w_hh,
                                            float* __restrict__ hfin,
                                            int layer, int write_y)
{
  const int c = blockIdx.x;           // 0..255
  const int d = c >> 7;
  const int b = c & 127;
  const int i = threadIdx.x;          // 0..63
  float w[H];
  const float* wrow = w_hh + ((size_t)(layer*2+d)*H + i)*H;
  #pragma unroll
  for (int j=0;j<H;++j) w[j] = wrow[j];
  const float* pb = pre + ((size_t)d*M + (size_t)b*S)*H + i;
  ushort_t* yb = y + (size_t)b*S*(2*H) + d*H + i;
  const int fwd = (d==0);
  int t = fwd ? 0 : S-1;
  const int dt = fwd ? 1 : -1;
  float h = 0.f;
  float pl0 = pb[(size_t)t*H];
  int t1 = t+dt; t1 = t1<0?0:(t1>S-1?S-1:t1);
  float pl1 = pb[(size_t)t1*H];
  for (int step=0; step<S; ++step){
    float acc = pl0;
    pl0 = pl1;
    int t2 = t + 2*dt; t2 = t2<0?0:(t2>S-1?S-1:t2);
    pl1 = pb[(size_t)t2*H];
    float s0=0.f,s1=0.f,s2=0.f,s3=0.f;
    #pragma unroll
    for (int j=0;j<H;j+=4){
      s0 = fmaf(w[j+0], bcast_lane(h,j+0), s0);
      s1 = fmaf(w[j+1], bcast_lane(h,j+1), s1);
      s2 = fmaf(w[j+2], bcast_lane(h,j+2), s2);
      s3 = fmaf(w[j+3], bcast_lane(h,j+3), s3);
    }
    acc += (s0+s1)+(s2+s3);
    h = fast_tanh(acc);
    if (write_y) yb[(size_t)t*(2*H)] = f2bf(h);
    t += dt;
  }
  hfin[((size_t)d*B + b)*H + i] = h;
}

// layers 1,2 input projection: [M,128]@[128,128]^T. Yin is bf16, W is fp32.
#define KC 32
__global__ __launch_bounds__(256) void k_gemm(const ushort_t* __restrict__ Yin,
     const float* __restrict__ w_ih, const float* __restrict__ b_ih,
     const float* __restrict__ b_hh, float* __restrict__ pre, int layer)
{
  __shared__ float sY[KC][132];
  __shared__ float sW[KC][132];
  const int tid = threadIdx.x;
  const int m0 = blockIdx.x * 128;
  const int tn = (tid & 15) * 8;
  const int tm = (tid >> 4) * 8;
  float acc[8][8];
  #pragma unroll
  for (int a=0;a<8;++a)
    #pragma unroll
    for (int q=0;q<8;++q) acc[a][q]=0.f;
  const float* Wb = w_ih + (size_t)layer*2*H*E;
  for (int kc=0; kc<E; kc+=KC){
    #pragma unroll
    for (int r=0;r<2;++r){
      int idx = r*256 + tid;     // 0..511
      int ym = idx >> 2;         // 0..127
      int yk = (idx & 3)*8;      // 0,8,16,24
      const ushort_t* p = Yin + (size_t)(m0+ym)*E + kc + yk;
      ushort4 a = *(const ushort4*)p;
      ushort4 bq = *(const ushort4*)(p+4);
      sY[yk+0][ym]=bf2f(a.x);  sY[yk+1][ym]=bf2f(a.y);  sY[yk+2][ym]=bf2f(a.z);  sY[yk+3][ym]=bf2f(a.w);
      sY[yk+4][ym]=bf2f(bq.x); sY[yk+5][ym]=bf2f(bq.y); sY[yk+6][ym]=bf2f(bq.z); sY[yk+7][ym]=bf2f(bq.w);
    }
    #pragma unroll
    for (int r=0;r<4;++r){
      int idx = r*256 + tid;     // 0..1023
      int wn = idx >> 3;         // 0..127
      int wk = (idx & 7)*4;      // 0..28
      float4 v = *(const float4*)(Wb + (size_t)wn*E + kc + wk);
      sW[wk+0][wn]=v.x; sW[wk+1][wn]=v.y; sW[wk+2][wn]=v.z; sW[wk+3][wn]=v.w;
    }
    __syncthreads();
    #pragma unroll 4
    for (int k=0;k<KC;++k){
      float4 a0 = *(const float4*)&sY[k][tm];
      float4 a1 = *(const float4*)&sY[k][tm+4];
      float4 b0 = *(const float4*)&sW[k][tn];
      float4 b1 = *(const float4*)&sW[k][tn+4];
      float am[8]={a0.x,a0.y,a0.z,a0.w,a1.x,a1.y,a1.z,a1.w};
      float bn[8]={b0.x,b0.y,b0.z,b0.w,b1.x,b1.y,b1.z,b1.w};
      #pragma unroll
      for (int mi=0;mi<8;++mi)
        #pragma unroll
        for (int ni=0;ni<8;++ni)
          acc[mi][ni] = fmaf(am[mi], bn[ni], acc[mi][ni]);
    }
    __syncthreads();
  }
  const int d = tn >> 6;
  const int i0 = tn & 63;
  float bias[8];
  #pragma unroll
  for (int ni=0;ni<8;++ni)
    bias[ni] = b_ih[(size_t)(layer*2+d)*H + i0+ni] + b_hh[(size_t)(layer*2+d)*H + i0+ni];
  #pragma unroll
  for (int mi=0;mi<8;++mi){
    size_t off = ((size_t)d*M + (m0+tm+mi))*H + i0;
    float4 o0 = make_float4(acc[mi][0]+bias[0], acc[mi][1]+bias[1], acc[mi][2]+bias[2], acc[mi][3]+bias[3]);
    float4 o1 = make_float4(acc[mi][4]+bias[4], acc[mi][5]+bias[5], acc[mi][6]+bias[6], acc[mi][7]+bias[7]);
    *(float4*)(pre + off)     = o0;
    *(float4*)(pre + off + 4) = o1;
  }
}

// final FC head; also reduces the 16 pool partials. fp32 in/out.
__global__ __launch_bounds__(128) void k_fc(const float* __restrict__ psum, const float* __restrict__ pmax,
    const float* __restrict__ hfin, const float* __restrict__ fc1_w, const float* __restrict__ fc1_b,
    const float* __restrict__ fc2_w, const float* __restrict__ fc2_b, float* __restrict__ out)
{
  const int b = blockIdx.x, tid = threadIdx.x;
  __shared__ __align__(16) float comb[384];
  __shared__ float red[2];
  float s=0.f, m=-INFINITY;
  #pragma unroll
  for (int c=0;c<16;++c){
    s += psum[((size_t)b*16+c)*E + tid];
    m = fmaxf(m, pmax[((size_t)b*16+c)*E + tid]);
  }
  comb[128+tid] = s*(1.f/2048.f);
  comb[256+tid] = m;
  comb[tid] = (tid<64) ? hfin[(size_t)b*H + tid] : hfin[((size_t)B + b)*H + (tid-64)];
  __syncthreads();
  float acc = fc1_b[tid];
  const float4* wrow = (const float4*)(fc1_w + (size_t)tid*384);
  const float4* cb = (const float4*)comb;
  #pragma unroll 8
  for (int k=0;k<96;++k){
    float4 wv = wrow[k]; float4 cv = cb[k];
    acc = fmaf(wv.x,cv.x,acc); acc = fmaf(wv.y,cv.y,acc);
    acc = fmaf(wv.z,cv.z,acc); acc = fmaf(wv.w,cv.w,acc);
  }
  acc = fmaxf(acc, 0.f);
  float p = acc * fc2_w[tid];
  #pragma unroll
  for (int off=32; off>0; off>>=1) p += __shfl_down(p, off);
  if ((tid & 63)==0) red[tid>>6] = p;
  __syncthreads();
  if (tid==0) out[b] = red[0] + red[1] + fc2_b[0];
}

extern "C" void kernel_launch(void* const* d_in, const int* in_sizes, int n_in,
                              void* d_out, int out_size, void* d_ws, size_t ws_size,
                              hipStream_t stream)
{
  const int*   x     = (const int*)  d_in[0];
  const float* emb   = (const float*)d_in[1];
  const float* w_ih  = (const float*)d_in[2];
  const float* w_hh  = (const float*)d_in[3];
  const float* b_ih  = (const float*)d_in[4];
  const float* b_hh  = (const float*)d_in[5];
  const float* fc1_w = (const float*)d_in[6];
  const float* fc1_b = (const float*)d_in[7];
  const float* fc2_w = (const float*)d_in[8];
  const float* fc2_b = (const float*)d_in[9];
  float* out = (float*)d_out;

  // workspace: keep under ~204 MB (270 MB faulted in round 1)
  char* ws = (char*)d_ws;
  float*    pre  = (float*)(ws);                                     // 2*M*H f32  = 134.2 MB
  ushort_t* y    = (ushort_t*)(ws + (size_t)2*M*H*4);                // M*128 bf16 =  67.1 MB
  float*    pe   = (float*)(ws + (size_t)2*M*H*4 + (size_t)M*128*2); // V*128 f32
  float*    psum = pe   + (size_t)V*128;                             // B*16*E f32
  float*    pmax = psum + (size_t)B*16*E;                            // B*16*E f32
  float*    hfin = pmax + (size_t)B*16*E;                            // 2*B*H f32

  k_pre_emb<<<V, 128, 0, stream>>>(emb, w_ih, b_ih, b_hh, pe);
  k_pool<<<dim3(B,16), 128, 0, stream>>>(x, emb, psum, pmax);
  k_gather0<<<M/4, 256, 0, stream>>>(x, pe, pre);
  k_rec<<<256, 64, 0, stream>>>(pre, y, w_hh, hfin, 0, 1);
  k_gemm<<<M/128, 256, 0, stream>>>(y, w_ih, b_ih, b_hh, pre, 1);
  k_rec<<<256, 64, 0, stream>>>(pre, y, w_hh, hfin, 1, 1);
  k_gemm<<<M/128, 256, 0, stream>>>(y, w_ih, b_ih, b_hh, pre, 2);
  k_rec<<<256, 64, 0, stream>>>(pre, y, w_hh, hfin, 2, 0);
  k_fc<<<B, 128, 0, stream>>>(psum, pmax, hfin, fc1_w, fc1_b, fc2_w, fc2_b, out);
}

// Round 5
// 2199.537 us; speedup vs baseline: 1.5595x; 1.5595x over previous
//
#include <hip/hip_runtime.h>
#include <math.h>

#define B 128
#define S 2048
#define V 800
#define E 128
#define H 64
#define NL 3
#define M (B*S)

typedef unsigned short ushort_t;

__device__ __forceinline__ float bf2f(unsigned short u){
  return __uint_as_float(((unsigned int)u) << 16);
}
__device__ __forceinline__ unsigned short f2bf(float f){
  unsigned int u = __float_as_uint(f);
  u += 0x7fff + ((u >> 16) & 1);          // round-to-nearest-even
  return (unsigned short)(u >> 16);
}
__device__ __forceinline__ float bcast_lane(float v, int j){
  return __int_as_float(__builtin_amdgcn_readlane(__float_as_int(v), j));
}
__device__ __forceinline__ float fast_tanh(float x){
  float e = __expf(2.f*x);
  return 1.f - 2.f*__builtin_amdgcn_rcpf(e+1.f);
}

// pre_emb[v][n] = emb[v]·w_ih[0,n,:] + b_ih[0,n] + b_hh[0,n],  n = d*64+i
__global__ __launch_bounds__(128) void k_pre_emb(const float* __restrict__ emb,
    const float* __restrict__ w_ih, const float* __restrict__ b_ih, const float* __restrict__ b_hh,
    float* __restrict__ pe)
{
  const int v = blockIdx.x;
  const int n = threadIdx.x;           // 0..127
  const float* er = emb + (size_t)v*E;
  const float* wr = w_ih + (size_t)n*E;   // layer 0 rows
  float acc = b_ih[n] + b_hh[n];
  #pragma unroll
  for (int e=0;e<E;e+=4){
    float4 ev = *(const float4*)(er+e);
    float4 wv = *(const float4*)(wr+e);
    acc = fmaf(ev.x, wv.x, acc);
    acc = fmaf(ev.y, wv.y, acc);
    acc = fmaf(ev.z, wv.z, acc);
    acc = fmaf(ev.w, wv.w, acc);
  }
  pe[(size_t)v*128 + n] = acc;
}

// partial mean/max pools over S-chunks
__global__ __launch_bounds__(128) void k_pool(const int* __restrict__ x, const float* __restrict__ emb,
      float* __restrict__ psum, float* __restrict__ pmax)
{
  const int b = blockIdx.x, c = blockIdx.y, e = threadIdx.x;
  const int* xb = x + (size_t)b*S + c*(S/16);
  float s=0.f, m=-INFINITY;
  for (int k=0;k<S/16;++k){
    int v = xb[k];
    float val = emb[(size_t)v*E + e];
    s += val; m = fmaxf(m,val);
  }
  psum[((size_t)b*16 + c)*E + e] = s;
  pmax[((size_t)b*16 + c)*E + e] = m;
}

// layer-0 input projection = gather from pre_emb table. pre[d][m][i]
__global__ __launch_bounds__(256) void k_gather0(const int* __restrict__ x, const float* __restrict__ pe,
      float* __restrict__ pre)
{
  const int m = blockIdx.x*4 + (threadIdx.x>>6);
  const int i = threadIdx.x & 63;
  const int v = x[m];
  const float* row = pe + (size_t)v*128;
  pre[(size_t)m*H + i]              = row[i];
  pre[((size_t)M + m)*H + i]        = row[64+i];
}

// recurrence: one wave per (d,b) chain. lane i owns output h[i]. y stored bf16.
// __launch_bounds__(64,1): 1 wave/EU min -> up to 512 VGPRs, keeps w[64] resident.
__global__ __launch_bounds__(64, 1) void k_rec(const float* __restrict__ pre,
                                               ushort_t* __restrict__ y,
                                               const float* __restrict__ w_hh,
                                               float* __restrict__ hfin,
                                               int layer, int write_y)
{
  const int c = blockIdx.x;           // 0..255
  const int d = c >> 7;
  const int b = c & 127;
  const int i = threadIdx.x;          // 0..63
  float w[H];                         // stays in VGPRs (launch_bounds(64,1))
  const float* wrow = w_hh + ((size_t)(layer*2+d)*H + i)*H;
  #pragma unroll
  for (int j=0;j<H;j+=4){
    float4 q = *(const float4*)(wrow+j);
    w[j]=q.x; w[j+1]=q.y; w[j+2]=q.z; w[j+3]=q.w;
  }
  const float* pb = pre + ((size_t)d*M + (size_t)b*S)*H + i;
  ushort_t* yb = y + (size_t)b*S*(2*H) + d*H + i;
  const int fwd = (d==0);
  int t = fwd ? 0 : S-1;
  const int dt = fwd ? 1 : -1;
  float h = 0.f;
  float pl0 = pb[(size_t)t*H];
  float pl1 = pb[(size_t)(t+dt)*H];   // S>=2 so t+dt always valid on first iter
  #pragma unroll 2
  for (int step=0; step<S; ++step){
    float acc = pl0;
    pl0 = pl1;
    int t2 = t + 2*dt; t2 = t2<0?0:(t2>S-1?S-1:t2);
    pl1 = pb[(size_t)t2*H];
    float s0=0.f,s1=0.f,s2=0.f,s3=0.f;
    #pragma unroll
    for (int j=0;j<H;j+=8){
      // batch 8 broadcasts, then 8 fmas across 4 chains: puts distance
      // between v_readlane (SGPR write) and its consuming v_fma.
      float b0 = bcast_lane(h,j+0), b1 = bcast_lane(h,j+1);
      float b2 = bcast_lane(h,j+2), b3 = bcast_lane(h,j+3);
      float b4 = bcast_lane(h,j+4), b5 = bcast_lane(h,j+5);
      float b6 = bcast_lane(h,j+6), b7 = bcast_lane(h,j+7);
      s0 = fmaf(w[j+0], b0, s0);
      s1 = fmaf(w[j+1], b1, s1);
      s2 = fmaf(w[j+2], b2, s2);
      s3 = fmaf(w[j+3], b3, s3);
      s0 = fmaf(w[j+4], b4, s0);
      s1 = fmaf(w[j+5], b5, s1);
      s2 = fmaf(w[j+6], b6, s2);
      s3 = fmaf(w[j+7], b7, s3);
    }
    acc += (s0+s1)+(s2+s3);
    h = fast_tanh(acc);
    if (write_y) yb[(size_t)t*(2*H)] = f2bf(h);
    t += dt;
  }
  hfin[((size_t)d*B + b)*H + i] = h;
}

// layers 1,2 input projection: [M,128]@[128,128]^T. Yin is bf16, W is fp32.
#define KC 32
__global__ __launch_bounds__(256) void k_gemm(const ushort_t* __restrict__ Yin,
     const float* __restrict__ w_ih, const float* __restrict__ b_ih,
     const float* __restrict__ b_hh, float* __restrict__ pre, int layer)
{
  __shared__ float sY[KC][132];
  __shared__ float sW[KC][132];
  const int tid = threadIdx.x;
  const int m0 = blockIdx.x * 128;
  const int tn = (tid & 15) * 8;
  const int tm = (tid >> 4) * 8;
  float acc[8][8];
  #pragma unroll
  for (int a=0;a<8;++a)
    #pragma unroll
    for (int q=0;q<8;++q) acc[a][q]=0.f;
  const float* Wb = w_ih + (size_t)layer*2*H*E;
  for (int kc=0; kc<E; kc+=KC){
    #pragma unroll
    for (int r=0;r<2;++r){
      int idx = r*256 + tid;     // 0..511
      int ym = idx >> 2;         // 0..127
      int yk = (idx & 3)*8;      // 0,8,16,24
      const ushort_t* p = Yin + (size_t)(m0+ym)*E + kc + yk;
      ushort4 a = *(const ushort4*)p;
      ushort4 bq = *(const ushort4*)(p+4);
      sY[yk+0][ym]=bf2f(a.x);  sY[yk+1][ym]=bf2f(a.y);  sY[yk+2][ym]=bf2f(a.z);  sY[yk+3][ym]=bf2f(a.w);
      sY[yk+4][ym]=bf2f(bq.x); sY[yk+5][ym]=bf2f(bq.y); sY[yk+6][ym]=bf2f(bq.z); sY[yk+7][ym]=bf2f(bq.w);
    }
    #pragma unroll
    for (int r=0;r<4;++r){
      int idx = r*256 + tid;     // 0..1023
      int wn = idx >> 3;         // 0..127
      int wk = (idx & 7)*4;      // 0..28
      float4 v = *(const float4*)(Wb + (size_t)wn*E + kc + wk);
      sW[wk+0][wn]=v.x; sW[wk+1][wn]=v.y; sW[wk+2][wn]=v.z; sW[wk+3][wn]=v.w;
    }
    __syncthreads();
    #pragma unroll 4
    for (int k=0;k<KC;++k){
      float4 a0 = *(const float4*)&sY[k][tm];
      float4 a1 = *(const float4*)&sY[k][tm+4];
      float4 b0 = *(const float4*)&sW[k][tn];
      float4 b1 = *(const float4*)&sW[k][tn+4];
      float am[8]={a0.x,a0.y,a0.z,a0.w,a1.x,a1.y,a1.z,a1.w};
      float bn[8]={b0.x,b0.y,b0.z,b0.w,b1.x,b1.y,b1.z,b1.w};
      #pragma unroll
      for (int mi=0;mi<8;++mi)
        #pragma unroll
        for (int ni=0;ni<8;++ni)
          acc[mi][ni] = fmaf(am[mi], bn[ni], acc[mi][ni]);
    }
    __syncthreads();
  }
  const int d = tn >> 6;
  const int i0 = tn & 63;
  float bias[8];
  #pragma unroll
  for (int ni=0;ni<8;++ni)
    bias[ni] = b_ih[(size_t)(layer*2+d)*H + i0+ni] + b_hh[(size_t)(layer*2+d)*H + i0+ni];
  #pragma unroll
  for (int mi=0;mi<8;++mi){
    size_t off = ((size_t)d*M + (m0+tm+mi))*H + i0;
    float4 o0 = make_float4(acc[mi][0]+bias[0], acc[mi][1]+bias[1], acc[mi][2]+bias[2], acc[mi][3]+bias[3]);
    float4 o1 = make_float4(acc[mi][4]+bias[4], acc[mi][5]+bias[5], acc[mi][6]+bias[6], acc[mi][7]+bias[7]);
    *(float4*)(pre + off)     = o0;
    *(float4*)(pre + off + 4) = o1;
  }
}

// final FC head; also reduces the 16 pool partials. fp32 in/out.
__global__ __launch_bounds__(128) void k_fc(const float* __restrict__ psum, const float* __restrict__ pmax,
    const float* __restrict__ hfin, const float* __restrict__ fc1_w, const float* __restrict__ fc1_b,
    const float* __restrict__ fc2_w, const float* __restrict__ fc2_b, float* __restrict__ out)
{
  const int b = blockIdx.x, tid = threadIdx.x;
  __shared__ __align__(16) float comb[384];
  __shared__ float red[2];
  float s=0.f, m=-INFINITY;
  #pragma unroll
  for (int c=0;c<16;++c){
    s += psum[((size_t)b*16+c)*E + tid];
    m = fmaxf(m, pmax[((size_t)b*16+c)*E + tid]);
  }
  comb[128+tid] = s*(1.f/2048.f);
  comb[256+tid] = m;
  comb[tid] = (tid<64) ? hfin[(size_t)b*H + tid] : hfin[((size_t)B + b)*H + (tid-64)];
  __syncthreads();
  float acc = fc1_b[tid];
  const float4* wrow = (const float4*)(fc1_w + (size_t)tid*384);
  const float4* cb = (const float4*)comb;
  #pragma unroll 8
  for (int k=0;k<96;++k){
    float4 wv = wrow[k]; float4 cv = cb[k];
    acc = fmaf(wv.x,cv.x,acc); acc = fmaf(wv.y,cv.y,acc);
    acc = fmaf(wv.z,cv.z,acc); acc = fmaf(wv.w,cv.w,acc);
  }
  acc = fmaxf(acc, 0.f);
  float p = acc * fc2_w[tid];
  #pragma unroll
  for (int off=32; off>0; off>>=1) p += __shfl_down(p, off);
  if ((tid & 63)==0) red[tid>>6] = p;
  __syncthreads();
  if (tid==0) out[b] = red[0] + red[1] + fc2_b[0];
}

extern "C" void kernel_launch(void* const* d_in, const int* in_sizes, int n_in,
                              void* d_out, int out_size, void* d_ws, size_t ws_size,
                              hipStream_t stream)
{
  const int*   x     = (const int*)  d_in[0];
  const float* emb   = (const float*)d_in[1];
  const float* w_ih  = (const float*)d_in[2];
  const float* w_hh  = (const float*)d_in[3];
  const float* b_ih  = (const float*)d_in[4];
  const float* b_hh  = (const float*)d_in[5];
  const float* fc1_w = (const float*)d_in[6];
  const float* fc1_b = (const float*)d_in[7];
  const float* fc2_w = (const float*)d_in[8];
  const float* fc2_b = (const float*)d_in[9];
  float* out = (float*)d_out;

  // workspace: keep under ~204 MB (270 MB faulted in round 1)
  char* ws = (char*)d_ws;
  float*    pre  = (float*)(ws);                                     // 2*M*H f32  = 134.2 MB
  ushort_t* y    = (ushort_t*)(ws + (size_t)2*M*H*4);                // M*128 bf16 =  67.1 MB
  float*    pe   = (float*)(ws + (size_t)2*M*H*4 + (size_t)M*128*2); // V*128 f32
  float*    psum = pe   + (size_t)V*128;                             // B*16*E f32
  float*    pmax = psum + (size_t)B*16*E;                            // B*16*E f32
  float*    hfin = pmax + (size_t)B*16*E;                            // 2*B*H f32

  k_pre_emb<<<V, 128, 0, stream>>>(emb, w_ih, b_ih, b_hh, pe);
  k_pool<<<dim3(B,16), 128, 0, stream>>>(x, emb, psum, pmax);
  k_gather0<<<M/4, 256, 0, stream>>>(x, pe, pre);
  k_rec<<<256, 64, 0, stream>>>(pre, y, w_hh, hfin, 0, 1);
  k_gemm<<<M/128, 256, 0, stream>>>(y, w_ih, b_ih, b_hh, pre, 1);
  k_rec<<<256, 64, 0, stream>>>(pre, y, w_hh, hfin, 1, 1);
  k_gemm<<<M/128, 256, 0, stream>>>(y, w_ih, b_ih, b_hh, pre, 2);
  k_rec<<<256, 64, 0, stream>>>(pre, y, w_hh, hfin, 2, 0);
  k_fc<<<B, 128, 0, stream>>>(psum, pmax, hfin, fc1_w, fc1_b, fc2_w, fc2_b, out);
}